// Round 11
// baseline (232.531 us; speedup 1.0000x reference)
//
#include <hip/hip_runtime.h>
#include <cstdint>
#include <cstddef>

// ---------------------------------------------------------------------------
// ChatGPTAttention: x[2,2048,1024] -> QKV proj -> causal MHA (16 heads, dk=64)
//                   -> O proj. bf16 MFMA pipeline, fp32 accumulate.
// Q is pre-scaled by 1/8 in the QKV-GEMM epilogue (cols < 1024).
// LESSONS: (R5) LDS row stride must be multiple of 8 ushorts (16B) for
// ds_read_b128. (R6/R8) DMA-staged LDS needs XOR source-swizzle. (R8/R9)
// in-block DMA pipelining only wins if occupancy is preserved (BK=32 dbuf).
// (R10) attn stuck ~46us across 3 structures; OccupancyPercent 11% — a
// 512-block grid caps at 2 blocks/CU regardless of LDS. R11: 1024-block
// grids everywhere; attn reads V^T frags straight from XCD-L2-resident vt
// (no V LDS), LDS 27.6KB -> ~4 blocks/CU.
// ---------------------------------------------------------------------------

typedef __attribute__((ext_vector_type(8))) short bf16x8;   // MFMA A/B frag
typedef __attribute__((ext_vector_type(4))) float f32x4;    // MFMA C/D frag
typedef __attribute__((ext_vector_type(4))) unsigned int u32x4;   // 16B copy
typedef __attribute__((ext_vector_type(4))) unsigned short u16x4; // 8B store
typedef __attribute__((ext_vector_type(8))) unsigned short u16x8; // 16B store

__device__ __forceinline__ unsigned short f2b(float f) {  // RNE f32->bf16
  unsigned int u = __float_as_uint(f);
  u = u + 0x7FFFu + ((u >> 16) & 1u);
  return (unsigned short)(u >> 16);
}
__device__ __forceinline__ unsigned short f2b_trunc(float f) {  // truncate
  return (unsigned short)(__float_as_uint(f) >> 16);
}

// async global->LDS DMA, 16B per lane; LDS dest = wave base + lane*16
__device__ __forceinline__ void gl_lds16(const unsigned short* g, unsigned short* s) {
  __builtin_amdgcn_global_load_lds((const __attribute__((address_space(1))) void*)g,
                                   (__attribute__((address_space(3))) void*)s, 16, 0, 0);
}

// ---------------- fp32 -> bf16, all three inputs in one launch -------------
__global__ __launch_bounds__(256) void cvt_all(const float* __restrict__ x,
                                               const float* __restrict__ wq,
                                               const float* __restrict__ wo,
                                               unsigned short* __restrict__ xb,
                                               unsigned short* __restrict__ wqb,
                                               unsigned short* __restrict__ wob) {
  const int bid = blockIdx.x;
  const float* in;
  unsigned short* out;
  int base;
  if (bid < 4096)      { in = x;  out = xb;  base = bid; }
  else if (bid < 7168) { in = wq; out = wqb; base = bid - 4096; }
  else                 { in = wo; out = wob; base = bid - 7168; }
  const int idx = (base * 256 + threadIdx.x) * 4;
  f32x4 v = *(const f32x4*)(in + idx);
  u16x4 r;
  r[0] = f2b(v[0]); r[1] = f2b(v[1]); r[2] = f2b(v[2]); r[3] = f2b(v[3]);
  *(u16x4*)(out + idx) = r;
}

// ---------------- GEMM: C[M,N] = (A[M,K] * W[N,K]^T + bias) * colscale -----
// 128x128 tile, BK=32, dbuf DMA (32KB LDS -> 4-5 blocks/CU + in-block
// pipeline). Unchanged from R10 (out of top-5).
__global__ __launch_bounds__(256) void gemm_bt(const unsigned short* __restrict__ A,
                                               const unsigned short* __restrict__ W,
                                               const float* __restrict__ bias,
                                               unsigned short* __restrict__ Cb,
                                               int M, int N, int K, int qcols) {
  __shared__ unsigned short As[2][128 * 32];
  __shared__ unsigned short Bs[2][128 * 32];
  const int tid  = threadIdx.x;
  const int lane = tid & 63;
  const int w    = tid >> 6;
  const int wy   = w >> 1, wx = w & 1;
  const int l15  = lane & 15, quad = lane >> 4;
  const int xr2  = (l15 >> 1) & 3;
  const int m0 = blockIdx.y * 128, n0 = blockIdx.x * 128;

  const unsigned short* gA[2];
  const unsigned short* gB[2];
  int off[2];
#pragma unroll
  for (int p = 0; p < 2; ++p) {
    const int c = tid + p * 256;
    const int r = c >> 2;
    const int srcc = (c & 3) ^ ((r >> 1) & 3);
    gA[p] = A + (size_t)(m0 + r) * K + srcc * 8;
    gB[p] = W + (size_t)(n0 + r) * K + srcc * 8;
    off[p] = c * 8;
  }

  f32x4 acc[4][4];
#pragma unroll
  for (int i = 0; i < 4; ++i)
#pragma unroll
    for (int j = 0; j < 4; ++j) acc[i][j] = (f32x4){0.f, 0.f, 0.f, 0.f};

#pragma unroll
  for (int p = 0; p < 2; ++p) {
    gl_lds16(gA[p], &As[0][off[p]]);
    gl_lds16(gB[p], &Bs[0][off[p]]);
  }

  const int NIT = K >> 5;
  for (int it = 0; it < NIT; ++it) {
    __syncthreads();
    const int cur = it & 1;
    if (it + 1 < NIT) {
      const int kt = (it + 1) << 5;
#pragma unroll
      for (int p = 0; p < 2; ++p) {
        gl_lds16(gA[p] + kt, &As[cur ^ 1][off[p]]);
        gl_lds16(gB[p] + kt, &Bs[cur ^ 1][off[p]]);
      }
    }
    const unsigned short* Ac = As[cur];
    const unsigned short* Bc = Bs[cur];
    bf16x8 af[4], bfr[4];
#pragma unroll
    for (int i = 0; i < 4; ++i)
      af[i] = *(const bf16x8*)&Ac[(wy * 64 + i * 16 + l15) * 32 + (quad ^ xr2) * 8];
#pragma unroll
    for (int j = 0; j < 4; ++j)
      bfr[j] = *(const bf16x8*)&Bc[(wx * 64 + j * 16 + l15) * 32 + (quad ^ xr2) * 8];
#pragma unroll
    for (int i = 0; i < 4; ++i)
#pragma unroll
      for (int j = 0; j < 4; ++j)
        acc[i][j] = __builtin_amdgcn_mfma_f32_16x16x32_bf16(af[i], bfr[j], acc[i][j], 0, 0, 0);
  }

#pragma unroll
  for (int i = 0; i < 4; ++i) {
    const int row = m0 + wy * 64 + i * 16 + quad * 4;
#pragma unroll
    for (int j = 0; j < 4; ++j) {
      const int col = n0 + wx * 64 + j * 16 + l15;
      const float bv = bias[col];
      const float sc = (col < qcols) ? 0.125f : 1.0f;
#pragma unroll
      for (int r = 0; r < 4; ++r)
        Cb[(size_t)(row + r) * N + col] = f2b((acc[i][j][r] + bv) * sc);
    }
  }
}

// ---------------- GEMM 64x64 tile, fp32 out (O-projection) -----------------
// R11: 64x64 tiles -> grid 16x64 = 1024 blocks (~4/CU, was 512 = 2/CU).
// BK=32 dbuf, 16KB LDS. 4 waves 2x2, each 32x32 (acc 2x2).
__global__ __launch_bounds__(256) void gemm_bt64(const unsigned short* __restrict__ A,
                                                 const unsigned short* __restrict__ W,
                                                 const float* __restrict__ bias,
                                                 float* __restrict__ Cf,
                                                 int M, int N, int K) {
  __shared__ unsigned short As[2][64 * 32];
  __shared__ unsigned short Bs[2][64 * 32];
  const int tid  = threadIdx.x;
  const int lane = tid & 63;
  const int w    = tid >> 6;
  const int wy   = w >> 1, wx = w & 1;
  const int l15  = lane & 15, quad = lane >> 4;
  const int xr2  = (l15 >> 1) & 3;
  const int m0 = blockIdx.y * 64, n0 = blockIdx.x * 64;

  const unsigned short* gA0;
  const unsigned short* gB0;
  int off0;
  {
    const int c = tid;  // 256 chunks per 64x32 tile: 1/thread for A and B
    const int r = c >> 2;
    const int srcc = (c & 3) ^ ((r >> 1) & 3);
    gA0 = A + (size_t)(m0 + r) * K + srcc * 8;
    gB0 = W + (size_t)(n0 + r) * K + srcc * 8;
    off0 = c * 8;
  }

  f32x4 acc[2][2];
#pragma unroll
  for (int i = 0; i < 2; ++i)
#pragma unroll
    for (int j = 0; j < 2; ++j) acc[i][j] = (f32x4){0.f, 0.f, 0.f, 0.f};

  gl_lds16(gA0, &As[0][off0]);
  gl_lds16(gB0, &Bs[0][off0]);

  const int NIT = K >> 5;
  for (int it = 0; it < NIT; ++it) {
    __syncthreads();
    const int cur = it & 1;
    if (it + 1 < NIT) {
      const int kt = (it + 1) << 5;
      gl_lds16(gA0 + kt, &As[cur ^ 1][off0]);
      gl_lds16(gB0 + kt, &Bs[cur ^ 1][off0]);
    }
    const unsigned short* Ac = As[cur];
    const unsigned short* Bc = Bs[cur];
    bf16x8 af[2], bfr[2];
#pragma unroll
    for (int i = 0; i < 2; ++i)
      af[i] = *(const bf16x8*)&Ac[(wy * 32 + i * 16 + l15) * 32 + (quad ^ xr2) * 8];
#pragma unroll
    for (int j = 0; j < 2; ++j)
      bfr[j] = *(const bf16x8*)&Bc[(wx * 32 + j * 16 + l15) * 32 + (quad ^ xr2) * 8];
#pragma unroll
    for (int i = 0; i < 2; ++i)
#pragma unroll
      for (int j = 0; j < 2; ++j)
        acc[i][j] = __builtin_amdgcn_mfma_f32_16x16x32_bf16(af[i], bfr[j], acc[i][j], 0, 0, 0);
  }

#pragma unroll
  for (int i = 0; i < 2; ++i) {
    const int row = m0 + wy * 32 + i * 16 + quad * 4;
#pragma unroll
    for (int j = 0; j < 2; ++j) {
      const int col = n0 + wx * 32 + j * 16 + l15;
      const float bv = bias[col];
#pragma unroll
      for (int r = 0; r < 4; ++r)
        Cf[(size_t)(row + r) * N + col] = acc[i][j][r] + bv;
    }
  }
}

// ---------------- V transpose: qkv V-part -> vt[(bh*64+d)][s] --------------
__global__ __launch_bounds__(256) void transpose_v(const unsigned short* __restrict__ qkv,
                                                   unsigned short* __restrict__ vt) {
  __shared__ unsigned short tile[64][72];
  const int tid = threadIdx.x;
  const int bh = blockIdx.y, b = bh >> 4, h = bh & 15;
  const int s0 = blockIdx.x * 64;
  const int i = tid >> 2;
  const int j = (tid & 3) * 16;
  const unsigned short* g = qkv + (size_t)(b * 2048 + s0 + i) * 3072 + 2048 + h * 64 + j;
  *(u32x4*)&tile[i][j]     = *(const u32x4*)g;
  *(u32x4*)&tile[i][j + 8] = *(const u32x4*)(g + 8);
  __syncthreads();
  const int d  = tid >> 2;
  const int sj = (tid & 3) * 16;
  u16x8 o0, o1;
#pragma unroll
  for (int k = 0; k < 8; ++k) { o0[k] = tile[sj + k][d]; o1[k] = tile[sj + 8 + k][d]; }
  unsigned short* gout = vt + (size_t)(bh * 64 + d) * 2048 + s0 + sj;
  *(u16x8*)gout       = o0;
  *(u16x8*)(gout + 8) = o1;
}

// ---------------- flash attention v8 ---------------------------------------
// 64 q-rows/block (4 waves x 16 q), grid (bh 32, qt 32) = 1024 blocks.
// XCD = bh%8 (K/V stream L2-resident); qt = 31-y (LPT). v7 MFMA structure:
// S^T = K Q^T (packed u16x4 P writes), O^T = V^T P^T, l via ones-A MFMA.
// V^T frags read DIRECTLY from global vt (L2-resident; issued post-barrier,
// consumed ~400cyc later) — no V LDS. LDS = Ks dbuf 18.4KB + pbuf 9.2KB =
// 27.6KB -> ~4 blocks/CU co-resident (R10: 512-block grid capped at 2).
__global__ __launch_bounds__(256, 4) void attn_fwd(const unsigned short* __restrict__ qkv,
                                                   const unsigned short* __restrict__ vt,
                                                   unsigned short* __restrict__ o) {
  __shared__ unsigned short Ks[2][64 * 72];
  __shared__ unsigned short pbuf[4][16 * 72];
  const int tid  = threadIdx.x;
  const int lane = tid & 63;
  const int w    = tid >> 6;
  const int l15  = lane & 15, quad = lane >> 4;
  const int bh = blockIdx.x, b = bh >> 4, h = bh & 15;
  const int qt = 31 - (int)blockIdx.y;  // LPT order
  const int q0 = qt * 64 + w * 16;
  const int T = qt + 1;

  const int srow = tid >> 2;
  const int scol = (tid & 3) * 16;
  const unsigned short* gK = qkv + (size_t)(b * 2048 + srow) * 3072 + 1024 + h * 64 + scol;
  const unsigned short* gV = vt + (size_t)(bh * 64) * 2048;

  // Q B-frags: B[n=q(l15)][k=d(quad*8+j)]
  const unsigned short* qr = qkv + (size_t)(b * 2048 + q0 + l15) * 3072 + h * 64;
  const bf16x8 bq0 = *(const bf16x8*)(qr + quad * 8);
  const bf16x8 bq1 = *(const bf16x8*)(qr + 32 + quad * 8);

  bf16x8 vones;
#pragma unroll
  for (int k = 0; k < 8; ++k) vones[k] = (short)0x3F80;  // bf16 1.0

  f32x4 acc[4];   // O^T C-layout: col=q(l15), row=d(j*16+quad*4+r)
#pragma unroll
  for (int j = 0; j < 4; ++j) acc[j] = (f32x4){0.f, 0.f, 0.f, 0.f};
  f32x4 accL = (f32x4){0.f, 0.f, 0.f, 0.f};

  unsigned short* P = pbuf[w];  // [q 0..15][kv 0..63], stride 72

  {  // prologue: stage K tile 0 into buf 0
    u32x4 k0 = *(const u32x4*)gK, k1 = *(const u32x4*)(gK + 8);
    unsigned short* sK = &Ks[0][srow * 72 + scol];
    *(u32x4*)sK = k0; *(u32x4*)(sK + 8) = k1;
  }

  for (int t = 0; t < T; ++t) {
    __syncthreads();  // Ks buf(t&1) staged; WAR-protects other buf rewrite
    const int cur = t & 1;
    const unsigned short* Kc = Ks[cur];
    const int kv0 = t * 64;
    // ---- V^T frags from global (L2): issue now, consumed at PV ----
    bf16x8 av[4][2];
#pragma unroll
    for (int j = 0; j < 4; ++j) {
      const unsigned short* vrow = gV + (size_t)(j * 16 + l15) * 2048 + kv0;
      av[j][0] = *(const bf16x8*)(vrow + quad * 8);
      av[j][1] = *(const bf16x8*)(vrow + 32 + quad * 8);
    }
    // ---- K register prefetch for t+1 ----
    u32x4 nk0, nk1;
    const bool more = (t + 1 < T);
    if (more) {
      const size_t ko = (size_t)(t + 1) * 64 * 3072;
      nk0 = *(const u32x4*)(gK + ko); nk1 = *(const u32x4*)(gK + ko + 8);
    }
    // ---- S^T[kv][q] = K Q^T ----
    f32x4 st[4];
#pragma unroll
    for (int n = 0; n < 4; ++n) {
      const bf16x8 kA0 = *(const bf16x8*)&Kc[(n * 16 + l15) * 72 + quad * 8];
      const bf16x8 kA1 = *(const bf16x8*)&Kc[(n * 16 + l15) * 72 + 32 + quad * 8];
      f32x4 z = (f32x4){0.f, 0.f, 0.f, 0.f};
      z = __builtin_amdgcn_mfma_f32_16x16x32_bf16(kA0, bq0, z, 0, 0, 0);
      z = __builtin_amdgcn_mfma_f32_16x16x32_bf16(kA1, bq1, z, 0, 0, 0);
      st[n] = z;
    }
    // ---- mask (edge only) + exp + packed P write ----
    if (kv0 + 63 > q0) {
      const int qrow = q0 + l15;
#pragma unroll
      for (int n = 0; n < 4; ++n)
#pragma unroll
        for (int r = 0; r < 4; ++r)
          if (kv0 + n * 16 + quad * 4 + r > qrow) st[n][r] = -1e30f;
    }
#pragma unroll
    for (int n = 0; n < 4; ++n) {
#pragma unroll
      for (int r = 0; r < 4; ++r) st[n][r] = __expf(st[n][r]);
      u16x4 pw;
      pw[0] = f2b_trunc(st[n][0]); pw[1] = f2b_trunc(st[n][1]);
      pw[2] = f2b_trunc(st[n][2]); pw[3] = f2b_trunc(st[n][3]);
      *(u16x4*)&P[l15 * 72 + n * 16 + quad * 4] = pw;  // in-wave WAR safe
    }
    // ---- O^T += V^T P^T ; l += 1 P^T ----
    const bf16x8 bp0 = *(const bf16x8*)&P[l15 * 72 + quad * 8];
    const bf16x8 bp1 = *(const bf16x8*)&P[l15 * 72 + 32 + quad * 8];
    accL = __builtin_amdgcn_mfma_f32_16x16x32_bf16(vones, bp0, accL, 0, 0, 0);
    accL = __builtin_amdgcn_mfma_f32_16x16x32_bf16(vones, bp1, accL, 0, 0, 0);
#pragma unroll
    for (int j = 0; j < 4; ++j) {
      acc[j] = __builtin_amdgcn_mfma_f32_16x16x32_bf16(av[j][0], bp0, acc[j], 0, 0, 0);
      acc[j] = __builtin_amdgcn_mfma_f32_16x16x32_bf16(av[j][1], bp1, acc[j], 0, 0, 0);
    }
    // ---- stage prefetched K into other buffer (WAR-safe past barrier) ----
    if (more) {
      unsigned short* sK = &Ks[cur ^ 1][srow * 72 + scol];
      *(u32x4*)sK = nk0; *(u32x4*)(sK + 8) = nk1;
    }
  }
  // ---- epilogue: lane holds q=l15, d=j*16+quad*4+r -> packed u16x4 ----
  const int qrow = q0 + l15;
  const float inv = 1.0f / accL[0];  // all rows of accL equal l[q]
  unsigned short* orow = o + (size_t)(b * 2048 + qrow) * 1024 + h * 64;
#pragma unroll
  for (int j = 0; j < 4; ++j) {
    u16x4 ov;
    ov[0] = f2b(acc[j][0] * inv); ov[1] = f2b(acc[j][1] * inv);
    ov[2] = f2b(acc[j][2] * inv); ov[3] = f2b(acc[j][3] * inv);
    *(u16x4*)(orow + j * 16 + quad * 4) = ov;
  }
}

// ---------------------------------------------------------------------------
extern "C" void kernel_launch(void* const* d_in, const int* in_sizes, int n_in,
                              void* d_out, int out_size, void* d_ws, size_t ws_size,
                              hipStream_t stream) {
  const float* x       = (const float*)d_in[0];
  // d_in[1] = mask: causal tril by construction; implemented analytically.
  const float* w_qkv_w = (const float*)d_in[2];
  const float* w_qkv_b = (const float*)d_in[3];
  const float* w_o_w   = (const float*)d_in[4];
  const float* w_o_b   = (const float*)d_in[5];
  float* out = (float*)d_out;

  unsigned short* ws    = (unsigned short*)d_ws;
  unsigned short* xb    = ws;                                  // 4096*1024
  unsigned short* wqb   = xb   + (size_t)4096 * 1024;          // 3072*1024
  unsigned short* wob   = wqb  + (size_t)3072 * 1024;          // 1024*1024
  unsigned short* qkvb  = wob  + (size_t)1024 * 1024;          // 4096*3072
  unsigned short* vtb   = qkvb + (size_t)4096 * 3072;          // 2048*2048
  unsigned short* attnb = vtb  + (size_t)2048 * 2048;          // 4096*1024

  cvt_all<<<8192, 256, 0, stream>>>(x, w_qkv_w, w_o_w, xb, wqb, wob);
  gemm_bt<<<dim3(24, 32), 256, 0, stream>>>(xb, wqb, w_qkv_b, qkvb, 4096, 3072, 1024, 1024);
  transpose_v<<<dim3(32, 32), 256, 0, stream>>>(qkvb, vtb);
  attn_fwd<<<dim3(32, 32), 256, 0, stream>>>(qkvb, vtb, attnb);
  gemm_bt64<<<dim3(16, 64), 256, 0, stream>>>(attnb, wob, w_o_b, out, 4096, 1024, 1024);
}

// Round 12
// 201.593 us; speedup vs baseline: 1.1535x; 1.1535x over previous
//
#include <hip/hip_runtime.h>
#include <cstdint>
#include <cstddef>

// ---------------------------------------------------------------------------
// ChatGPTAttention: x[2,2048,1024] -> QKV proj -> causal MHA (16 heads, dk=64)
//                   -> O proj. bf16 MFMA pipeline, fp32 accumulate.
// Q is pre-scaled by 1/8 in the QKV-GEMM epilogue (cols < 1024).
// LESSONS: (R5) LDS row stride must be multiple of 8 ushorts (16B) for
// ds_read_b128. (R6/R8) DMA-staged LDS needs XOR source-swizzle. (R8/R9)
// dbuf DMA pipelining only wins if occupancy preserved (BK=32). (R11)
// per-wave global V frags at 4x redundancy serialize on vmcnt — only do
// per-wave global frags at 1x redundancy. (R7..R11) attn floor ~46us was
// LDS-pipe INSTRUCTIONS: 4-wave blocks re-issue the same frag reads 4x.
// R12 v9: 1-wave blocks (64 thr), 32q/wave, ZERO barriers: K via DMA-dbuf
// LDS (swizzled), V direct-global 1x, P reused in-wave. 20 LDS ops/trip.
// ---------------------------------------------------------------------------

typedef __attribute__((ext_vector_type(8))) short bf16x8;   // MFMA A/B frag
typedef __attribute__((ext_vector_type(4))) float f32x4;    // MFMA C/D frag
typedef __attribute__((ext_vector_type(4))) unsigned int u32x4;   // 16B copy
typedef __attribute__((ext_vector_type(4))) unsigned short u16x4; // 8B store
typedef __attribute__((ext_vector_type(8))) unsigned short u16x8; // 16B store

__device__ __forceinline__ unsigned short f2b(float f) {  // RNE f32->bf16
  unsigned int u = __float_as_uint(f);
  u = u + 0x7FFFu + ((u >> 16) & 1u);
  return (unsigned short)(u >> 16);
}
__device__ __forceinline__ unsigned short f2b_trunc(float f) {  // truncate
  return (unsigned short)(__float_as_uint(f) >> 16);
}

// async global->LDS DMA, 16B per lane; LDS dest = wave base + lane*16
__device__ __forceinline__ void gl_lds16(const unsigned short* g, unsigned short* s) {
  __builtin_amdgcn_global_load_lds((const __attribute__((address_space(1))) void*)g,
                                   (__attribute__((address_space(3))) void*)s, 16, 0, 0);
}

// ---------------- fp32 -> bf16, all three inputs in one launch -------------
__global__ __launch_bounds__(256) void cvt_all(const float* __restrict__ x,
                                               const float* __restrict__ wq,
                                               const float* __restrict__ wo,
                                               unsigned short* __restrict__ xb,
                                               unsigned short* __restrict__ wqb,
                                               unsigned short* __restrict__ wob) {
  const int bid = blockIdx.x;
  const float* in;
  unsigned short* out;
  int base;
  if (bid < 4096)      { in = x;  out = xb;  base = bid; }
  else if (bid < 7168) { in = wq; out = wqb; base = bid - 4096; }
  else                 { in = wo; out = wob; base = bid - 7168; }
  const int idx = (base * 256 + threadIdx.x) * 4;
  f32x4 v = *(const f32x4*)(in + idx);
  u16x4 r;
  r[0] = f2b(v[0]); r[1] = f2b(v[1]); r[2] = f2b(v[2]); r[3] = f2b(v[3]);
  *(u16x4*)(out + idx) = r;
}

// ---------------- GEMM: C[M,N] = (A[M,K] * W[N,K]^T + bias) * colscale -----
// 128x128 tile, BK=32, dbuf DMA (32KB LDS). Unchanged from R10.
__global__ __launch_bounds__(256) void gemm_bt(const unsigned short* __restrict__ A,
                                               const unsigned short* __restrict__ W,
                                               const float* __restrict__ bias,
                                               unsigned short* __restrict__ Cb,
                                               int M, int N, int K, int qcols) {
  __shared__ unsigned short As[2][128 * 32];
  __shared__ unsigned short Bs[2][128 * 32];
  const int tid  = threadIdx.x;
  const int lane = tid & 63;
  const int w    = tid >> 6;
  const int wy   = w >> 1, wx = w & 1;
  const int l15  = lane & 15, quad = lane >> 4;
  const int xr2  = (l15 >> 1) & 3;
  const int m0 = blockIdx.y * 128, n0 = blockIdx.x * 128;

  const unsigned short* gA[2];
  const unsigned short* gB[2];
  int off[2];
#pragma unroll
  for (int p = 0; p < 2; ++p) {
    const int c = tid + p * 256;
    const int r = c >> 2;
    const int srcc = (c & 3) ^ ((r >> 1) & 3);
    gA[p] = A + (size_t)(m0 + r) * K + srcc * 8;
    gB[p] = W + (size_t)(n0 + r) * K + srcc * 8;
    off[p] = c * 8;
  }

  f32x4 acc[4][4];
#pragma unroll
  for (int i = 0; i < 4; ++i)
#pragma unroll
    for (int j = 0; j < 4; ++j) acc[i][j] = (f32x4){0.f, 0.f, 0.f, 0.f};

#pragma unroll
  for (int p = 0; p < 2; ++p) {
    gl_lds16(gA[p], &As[0][off[p]]);
    gl_lds16(gB[p], &Bs[0][off[p]]);
  }

  const int NIT = K >> 5;
  for (int it = 0; it < NIT; ++it) {
    __syncthreads();
    const int cur = it & 1;
    if (it + 1 < NIT) {
      const int kt = (it + 1) << 5;
#pragma unroll
      for (int p = 0; p < 2; ++p) {
        gl_lds16(gA[p] + kt, &As[cur ^ 1][off[p]]);
        gl_lds16(gB[p] + kt, &Bs[cur ^ 1][off[p]]);
      }
    }
    const unsigned short* Ac = As[cur];
    const unsigned short* Bc = Bs[cur];
    bf16x8 af[4], bfr[4];
#pragma unroll
    for (int i = 0; i < 4; ++i)
      af[i] = *(const bf16x8*)&Ac[(wy * 64 + i * 16 + l15) * 32 + (quad ^ xr2) * 8];
#pragma unroll
    for (int j = 0; j < 4; ++j)
      bfr[j] = *(const bf16x8*)&Bc[(wx * 64 + j * 16 + l15) * 32 + (quad ^ xr2) * 8];
#pragma unroll
    for (int i = 0; i < 4; ++i)
#pragma unroll
      for (int j = 0; j < 4; ++j)
        acc[i][j] = __builtin_amdgcn_mfma_f32_16x16x32_bf16(af[i], bfr[j], acc[i][j], 0, 0, 0);
  }

#pragma unroll
  for (int i = 0; i < 4; ++i) {
    const int row = m0 + wy * 64 + i * 16 + quad * 4;
#pragma unroll
    for (int j = 0; j < 4; ++j) {
      const int col = n0 + wx * 64 + j * 16 + l15;
      const float bv = bias[col];
      const float sc = (col < qcols) ? 0.125f : 1.0f;
#pragma unroll
      for (int r = 0; r < 4; ++r)
        Cb[(size_t)(row + r) * N + col] = f2b((acc[i][j][r] + bv) * sc);
    }
  }
}

// ---------------- GEMM 64x64 tile, fp32 out (O-projection) -----------------
// Grid 16x64 = 1024 blocks, BK=32 dbuf, 16KB LDS. Unchanged from R11.
__global__ __launch_bounds__(256) void gemm_bt64(const unsigned short* __restrict__ A,
                                                 const unsigned short* __restrict__ W,
                                                 const float* __restrict__ bias,
                                                 float* __restrict__ Cf,
                                                 int M, int N, int K) {
  __shared__ unsigned short As[2][64 * 32];
  __shared__ unsigned short Bs[2][64 * 32];
  const int tid  = threadIdx.x;
  const int lane = tid & 63;
  const int w    = tid >> 6;
  const int wy   = w >> 1, wx = w & 1;
  const int l15  = lane & 15, quad = lane >> 4;
  const int xr2  = (l15 >> 1) & 3;
  const int m0 = blockIdx.y * 64, n0 = blockIdx.x * 64;

  const unsigned short* gA0;
  const unsigned short* gB0;
  int off0;
  {
    const int c = tid;
    const int r = c >> 2;
    const int srcc = (c & 3) ^ ((r >> 1) & 3);
    gA0 = A + (size_t)(m0 + r) * K + srcc * 8;
    gB0 = W + (size_t)(n0 + r) * K + srcc * 8;
    off0 = c * 8;
  }

  f32x4 acc[2][2];
#pragma unroll
  for (int i = 0; i < 2; ++i)
#pragma unroll
    for (int j = 0; j < 2; ++j) acc[i][j] = (f32x4){0.f, 0.f, 0.f, 0.f};

  gl_lds16(gA0, &As[0][off0]);
  gl_lds16(gB0, &Bs[0][off0]);

  const int NIT = K >> 5;
  for (int it = 0; it < NIT; ++it) {
    __syncthreads();
    const int cur = it & 1;
    if (it + 1 < NIT) {
      const int kt = (it + 1) << 5;
      gl_lds16(gA0 + kt, &As[cur ^ 1][off0]);
      gl_lds16(gB0 + kt, &Bs[cur ^ 1][off0]);
    }
    const unsigned short* Ac = As[cur];
    const unsigned short* Bc = Bs[cur];
    bf16x8 af[2], bfr[2];
#pragma unroll
    for (int i = 0; i < 2; ++i)
      af[i] = *(const bf16x8*)&Ac[(wy * 32 + i * 16 + l15) * 32 + (quad ^ xr2) * 8];
#pragma unroll
    for (int j = 0; j < 2; ++j)
      bfr[j] = *(const bf16x8*)&Bc[(wx * 32 + j * 16 + l15) * 32 + (quad ^ xr2) * 8];
#pragma unroll
    for (int i = 0; i < 2; ++i)
#pragma unroll
      for (int j = 0; j < 2; ++j)
        acc[i][j] = __builtin_amdgcn_mfma_f32_16x16x32_bf16(af[i], bfr[j], acc[i][j], 0, 0, 0);
  }

#pragma unroll
  for (int i = 0; i < 2; ++i) {
    const int row = m0 + wy * 32 + i * 16 + quad * 4;
#pragma unroll
    for (int j = 0; j < 2; ++j) {
      const int col = n0 + wx * 32 + j * 16 + l15;
      const float bv = bias[col];
#pragma unroll
      for (int r = 0; r < 4; ++r)
        Cf[(size_t)(row + r) * N + col] = acc[i][j][r] + bv;
    }
  }
}

// ---------------- V transpose: qkv V-part -> vt[(bh*64+d)][s] --------------
__global__ __launch_bounds__(256) void transpose_v(const unsigned short* __restrict__ qkv,
                                                   unsigned short* __restrict__ vt) {
  __shared__ unsigned short tile[64][72];
  const int tid = threadIdx.x;
  const int bh = blockIdx.y, b = bh >> 4, h = bh & 15;
  const int s0 = blockIdx.x * 64;
  const int i = tid >> 2;
  const int j = (tid & 3) * 16;
  const unsigned short* g = qkv + (size_t)(b * 2048 + s0 + i) * 3072 + 2048 + h * 64 + j;
  *(u32x4*)&tile[i][j]     = *(const u32x4*)g;
  *(u32x4*)&tile[i][j + 8] = *(const u32x4*)(g + 8);
  __syncthreads();
  const int d  = tid >> 2;
  const int sj = (tid & 3) * 16;
  u16x8 o0, o1;
#pragma unroll
  for (int k = 0; k < 8; ++k) { o0[k] = tile[sj + k][d]; o1[k] = tile[sj + 8 + k][d]; }
  unsigned short* gout = vt + (size_t)(bh * 64 + d) * 2048 + s0 + sj;
  *(u16x8*)gout       = o0;
  *(u16x8*)(gout + 8) = o1;
}

// ---------------- flash attention v9: 1-wave blocks, zero barriers ---------
// Block = 64 threads = 1 wave, 32 q-rows. Grid (bh 32, qt 64) = 2048 waves
// (XCD = bh%8 -> K/V stream XCD-L2-resident; qt = 63-y LPT). Per trip:
//  [issue V^T frags from global, 1x redundancy — BEFORE K-DMA so in-order
//   vmcnt retirement doesn't chain them]
//  [issue K(t+1) DMA -> Ks[buf^1], XOR-swizzled packed [64][64] layout]
//  S^T = K Q^T (K frags from swizzled LDS) -> mask/exp -> P (one 16x72
//  buffer reused for both q-subtiles; in-wave DS ordering = WAR-safe)
//  -> O^T += V^T P^T, l += 1 P^T.  __syncthreads() = cheap 1-wave DMA drain.
// LDS 18.7KB -> 8 blocks/CU = 8 independent waves/CU; 20 LDS ops/trip
// (4-wave designs: ~28-35/wave for the same work — that was the 46us floor).
__global__ __launch_bounds__(64, 2) void attn_fwd(const unsigned short* __restrict__ qkv,
                                                  const unsigned short* __restrict__ vt,
                                                  unsigned short* __restrict__ o) {
  __shared__ unsigned short Ks[2][64 * 64];  // packed DMA layout, XOR-swizzled
  __shared__ unsigned short P[16 * 72];
  const int lane = threadIdx.x;              // single wave
  const int l15 = lane & 15, quad = lane >> 4;
  const int xr = l15 & 7;
  const int bh = blockIdx.x, b = bh >> 4, h = bh & 15;
  const int qt = 63 - (int)blockIdx.y;       // LPT: heavy blocks first
  const int q0 = qt * 32;
  const int T = (qt >> 1) + 1;               // 64-kv tiles covering q0+31

  // K DMA source map: chunk c = p*64+lane: row=c>>3, col3=c&7,
  // swizzled source col = col3 ^ (row&7); LDS dest byte = c*16 (DMA-fixed).
  const unsigned short* gK[8];
#pragma unroll
  for (int p = 0; p < 8; ++p) {
    const int c = p * 64 + lane;
    const int r = c >> 3;
    const int sc = ((c & 7) ^ (r & 7)) * 8;
    gK[p] = qkv + (size_t)(b * 2048 + r) * 3072 + 1024 + h * 64 + sc;
  }

  // Q B-frags: 2 q-subtiles of 16; B[n=q(l15)][k=d(quad*8+j)]
  const unsigned short* qr0 = qkv + (size_t)(b * 2048 + q0 + l15) * 3072 + h * 64;
  const unsigned short* qr1 = qr0 + (size_t)16 * 3072;
  const bf16x8 bq[2][2] = {
    { *(const bf16x8*)(qr0 + quad * 8), *(const bf16x8*)(qr0 + 32 + quad * 8) },
    { *(const bf16x8*)(qr1 + quad * 8), *(const bf16x8*)(qr1 + 32 + quad * 8) } };

  const unsigned short* gV = vt + (size_t)(bh * 64) * 2048;

  bf16x8 vones;
#pragma unroll
  for (int k = 0; k < 8; ++k) vones[k] = (short)0x3F80;  // bf16 1.0

  f32x4 acc[2][4];   // O^T C-layout: col=q(l15), row=d(j*16+quad*4+r)
#pragma unroll
  for (int i = 0; i < 2; ++i)
#pragma unroll
    for (int j = 0; j < 4; ++j) acc[i][j] = (f32x4){0.f, 0.f, 0.f, 0.f};
  f32x4 accL[2] = {(f32x4){0.f, 0.f, 0.f, 0.f}, (f32x4){0.f, 0.f, 0.f, 0.f}};

  // prologue: DMA K tile 0 -> buf 0
#pragma unroll
  for (int p = 0; p < 8; ++p) gl_lds16(gK[p], &Ks[0][p * 512]);

  for (int t = 0; t < T; ++t) {
    __syncthreads();  // 1-wave: cheap vmcnt drain of K DMA for buf(t&1)
    const int cur = t & 1;
    const int kv0 = t * 64;
    // ---- V^T A-frags direct from global (1x; issued BEFORE next DMA) ----
    bf16x8 av[4][2];
#pragma unroll
    for (int j = 0; j < 4; ++j) {
      const unsigned short* vrow = gV + (size_t)(j * 16 + l15) * 2048 + kv0;
      av[j][0] = *(const bf16x8*)(vrow + quad * 8);
      av[j][1] = *(const bf16x8*)(vrow + 32 + quad * 8);
    }
    // ---- issue K(t+1) DMA into other buffer; drained at next trip ----
    if (t + 1 < T) {
      const size_t ko = (size_t)(t + 1) * 64 * 3072;
#pragma unroll
      for (int p = 0; p < 8; ++p) gl_lds16(gK[p] + ko, &Ks[cur ^ 1][p * 512]);
    }
    // ---- K A-frags from swizzled LDS ----
    const unsigned short* Kc = Ks[cur];
    bf16x8 kA[4][2];
#pragma unroll
    for (int n = 0; n < 4; ++n) {
      const int row = n * 16 + l15;
      kA[n][0] = *(const bf16x8*)&Kc[row * 64 + ((quad) ^ xr) * 8];
      kA[n][1] = *(const bf16x8*)&Kc[row * 64 + ((4 + quad) ^ xr) * 8];
    }
    // ---- per 16-q subtile: S^T -> mask/exp -> P -> PV ----
#pragma unroll
    for (int qs = 0; qs < 2; ++qs) {
      f32x4 st[4];
#pragma unroll
      for (int n = 0; n < 4; ++n) {
        f32x4 z = (f32x4){0.f, 0.f, 0.f, 0.f};
        z = __builtin_amdgcn_mfma_f32_16x16x32_bf16(kA[n][0], bq[qs][0], z, 0, 0, 0);
        z = __builtin_amdgcn_mfma_f32_16x16x32_bf16(kA[n][1], bq[qs][1], z, 0, 0, 0);
        st[n] = z;
      }
      const int qbase = q0 + qs * 16;
      if (kv0 + 63 > qbase) {
        const int qrow = qbase + l15;
#pragma unroll
        for (int n = 0; n < 4; ++n)
#pragma unroll
          for (int r = 0; r < 4; ++r)
            if (kv0 + n * 16 + quad * 4 + r > qrow) st[n][r] = -1e30f;
      }
#pragma unroll
      for (int n = 0; n < 4; ++n) {
#pragma unroll
        for (int r = 0; r < 4; ++r) st[n][r] = __expf(st[n][r]);
        u16x4 pw;
        pw[0] = f2b_trunc(st[n][0]); pw[1] = f2b_trunc(st[n][1]);
        pw[2] = f2b_trunc(st[n][2]); pw[3] = f2b_trunc(st[n][3]);
        *(u16x4*)&P[l15 * 72 + n * 16 + quad * 4] = pw;  // in-wave WAR safe
      }
      const bf16x8 bp0 = *(const bf16x8*)&P[l15 * 72 + quad * 8];
      const bf16x8 bp1 = *(const bf16x8*)&P[l15 * 72 + 32 + quad * 8];
      accL[qs] = __builtin_amdgcn_mfma_f32_16x16x32_bf16(vones, bp0, accL[qs], 0, 0, 0);
      accL[qs] = __builtin_amdgcn_mfma_f32_16x16x32_bf16(vones, bp1, accL[qs], 0, 0, 0);
#pragma unroll
      for (int j = 0; j < 4; ++j) {
        acc[qs][j] = __builtin_amdgcn_mfma_f32_16x16x32_bf16(av[j][0], bp0, acc[qs][j], 0, 0, 0);
        acc[qs][j] = __builtin_amdgcn_mfma_f32_16x16x32_bf16(av[j][1], bp1, acc[qs][j], 0, 0, 0);
      }
    }
  }
  // ---- epilogue: lane holds q=l15, d=j*16+quad*4+r -> packed u16x4 ----
#pragma unroll
  for (int qs = 0; qs < 2; ++qs) {
    const int qrow = q0 + qs * 16 + l15;
    const float inv = 1.0f / accL[qs][0];  // all rows of accL equal l[q]
    unsigned short* orow = o + (size_t)(b * 2048 + qrow) * 1024 + h * 64;
#pragma unroll
    for (int j = 0; j < 4; ++j) {
      u16x4 ov;
      ov[0] = f2b(acc[qs][j][0] * inv); ov[1] = f2b(acc[qs][j][1] * inv);
      ov[2] = f2b(acc[qs][j][2] * inv); ov[3] = f2b(acc[qs][j][3] * inv);
      *(u16x4*)(orow + j * 16 + quad * 4) = ov;
    }
  }
}

// ---------------------------------------------------------------------------
extern "C" void kernel_launch(void* const* d_in, const int* in_sizes, int n_in,
                              void* d_out, int out_size, void* d_ws, size_t ws_size,
                              hipStream_t stream) {
  const float* x       = (const float*)d_in[0];
  // d_in[1] = mask: causal tril by construction; implemented analytically.
  const float* w_qkv_w = (const float*)d_in[2];
  const float* w_qkv_b = (const float*)d_in[3];
  const float* w_o_w   = (const float*)d_in[4];
  const float* w_o_b   = (const float*)d_in[5];
  float* out = (float*)d_out;

  unsigned short* ws    = (unsigned short*)d_ws;
  unsigned short* xb    = ws;                                  // 4096*1024
  unsigned short* wqb   = xb   + (size_t)4096 * 1024;          // 3072*1024
  unsigned short* wob   = wqb  + (size_t)3072 * 1024;          // 1024*1024
  unsigned short* qkvb  = wob  + (size_t)1024 * 1024;          // 4096*3072
  unsigned short* vtb   = qkvb + (size_t)4096 * 3072;          // 2048*2048
  unsigned short* attnb = vtb  + (size_t)2048 * 2048;          // 4096*1024

  cvt_all<<<8192, 256, 0, stream>>>(x, w_qkv_w, w_o_w, xb, wqb, wob);
  gemm_bt<<<dim3(24, 32), 256, 0, stream>>>(xb, wqb, w_qkv_b, qkvb, 4096, 3072, 1024, 1024);
  transpose_v<<<dim3(32, 32), 256, 0, stream>>>(qkvb, vtb);
  attn_fwd<<<dim3(32, 64), 64, 0, stream>>>(qkvb, vtb, attnb);
  gemm_bt64<<<dim3(16, 64), 256, 0, stream>>>(attnb, wob, w_o_b, out, 4096, 1024, 1024);
}